// Round 12
// baseline (1742.803 us; speedup 1.0000x reference)
//
#include <hip/hip_runtime.h>
#include <hip/hip_bf16.h>

// krignn2: out = C_qk @ inv(C_kk) @ (VALUE*mlp_v(VALUE))
// C_kk = exp(-cdist(Ks,Ks)) + 1e-3 I,  Ks = KEY*mlp(KEY), Qs = QUERY*mlp(QUERY).
// Blocked fp32 Cholesky + inverted diag blocks + fused fwd/parallel bwd solve.
// R12: (a) syrkc launches eliminated — potf(s) applies the (0,0) syrk itself as a
//      prologue (T -= Lp Lp^T in LDS); ALL other syrk(s-1) pairs ride potf(s).
//      2 launches/step, 27 dispatches total (was 34; gaps ~8us each).
//      (b) potf core rewritten 32-blocked: one wave factors+inverts each 32x32
//      diag sub-block in registers via shfl (symmetry: L[j][i]=a[i]*rs, no extra
//      broadcast); trsm32/syrk32 parallel across 256 threads; diag inverses are
//      byproducts (trtri ph2 deleted). Barriers ~70 -> ~30.
//      Invariant: diag blocks kept fully symmetric in global (syrk diag pairs
//      write full square) so potf loads the full tile without mirroring.

__device__ __forceinline__ int row_of(int e) {
    int i = (int)((sqrtf(8.0f * (float)e + 1.0f) - 1.0f) * 0.5f);
    while ((i + 1) * (i + 2) / 2 <= e) i++;
    while (i * (i + 1) / 2 > e) i--;
    return i;
}

// ---------------- transpose W2 / Wv2 (for coalesced layer-2 reads) -------------
__global__ void k_transpose(const float* __restrict__ W2, const float* __restrict__ Wv2,
                            float* __restrict__ W2T, float* __restrict__ Wv2T) {
    int tid = blockIdx.x * 256 + threadIdx.x;   // 0..32767
    int e = tid & 16383;
    int r = e >> 7, c = e & 127;
    if (tid < 16384) W2T[c * 128 + r] = W2[e];
    else             Wv2T[c * 128 + r] = Wv2[e];
}

// ---------------- MLP body (Linear->ReLU->Linear->ReLU->Linear) + scale --------
template<int DI, int P>
__device__ __forceinline__ void mlp_body(const float* __restrict__ in,
                                         float* __restrict__ out, int base,
                                         const float* __restrict__ W1,
                                         const float* __restrict__ b1,
                                         const float* __restrict__ W2T,
                                         const float* __restrict__ b2,
                                         const float* __restrict__ W3,
                                         const float* __restrict__ b3) {
    __shared__ float xs[P][DI];
    __shared__ float h1[P][128];
    __shared__ float h2[P][129];
    int t = threadIdx.x;
    for (int i = t; i < P * DI; i += 128) xs[i / DI][i % DI] = in[base * DI + i];
    __syncthreads();
    float w1r[DI];
#pragma unroll
    for (int d = 0; d < DI; d++) w1r[d] = W1[t * DI + d];
    float b1t = b1[t], b2t = b2[t];
#pragma unroll
    for (int p = 0; p < P; p++) {
        float s = b1t;
#pragma unroll
        for (int d = 0; d < DI; d++) s += w1r[d] * xs[p][d];
        h1[p][t] = fmaxf(s, 0.0f);
    }
    __syncthreads();
    float acc[P];
#pragma unroll
    for (int p = 0; p < P; p++) acc[p] = b2t;
    for (int k = 0; k < 128; k++) {
        float w = W2T[k * 128 + t];
#pragma unroll
        for (int p = 0; p < P; p++) acc[p] += w * h1[p][k];
    }
#pragma unroll
    for (int p = 0; p < P; p++) h2[p][t] = fmaxf(acc[p], 0.0f);
    __syncthreads();
    if (t < P * DI) {
        int p = t / DI, d = t % DI;
        float s = b3[d];
        for (int k = 0; k < 128; k++) s += W3[d * 128 + k] * h2[p][k];
        int gi = base * DI + t;
        out[gi] = in[gi] * s;
    }
}

__global__ void k_mlp_kq(const float* __restrict__ KEY, float* __restrict__ Ks,
                         const float* __restrict__ QUERY, float* __restrict__ Qs,
                         const float* __restrict__ W1, const float* __restrict__ b1,
                         const float* __restrict__ W2T, const float* __restrict__ b2,
                         const float* __restrict__ W3, const float* __restrict__ b3) {
    if (blockIdx.x < 512)
        mlp_body<3, 32>(KEY, Ks, blockIdx.x * 32, W1, b1, W2T, b2, W3, b3);
    else
        mlp_body<3, 32>(QUERY, Qs, (blockIdx.x - 512) * 32, W1, b1, W2T, b2, W3, b3);
}

__global__ void k_mlp_v(const float* __restrict__ VALUE, float* __restrict__ Vs,
                        const float* __restrict__ W1, const float* __restrict__ b1,
                        const float* __restrict__ W2T, const float* __restrict__ b2,
                        const float* __restrict__ W3, const float* __restrict__ b3) {
    mlp_body<8, 16>(VALUE, Vs, blockIdx.x * 16, W1, b1, W2T, b2, W3, b3);
}

// ---------------- build C_kk = exp(-dist) + nugget*I ---------------------------
__global__ void k_buildC(const float* __restrict__ Ks, float* __restrict__ C) {
    long idx = (long)blockIdx.x * 256 + threadIdx.x;  // 16M elements
    int b = (int)(idx >> 20);
    int rem = (int)(idx & 1048575);
    int i = rem >> 10, j = rem & 1023;
    const float* a = Ks + ((long)b * 1024 + i) * 3;
    const float* bb = Ks + ((long)b * 1024 + j) * 3;
    float d0 = a[0] - bb[0], d1 = a[1] - bb[1], d2 = a[2] - bb[2];
    float dist = sqrtf(d0 * d0 + d1 * d1 + d2 * d2 + 1e-12f);
    float v = __expf(-dist);
    if (i == j) v += 1e-3f;
    C[idx] = v;
}

// ---------------- potf body v2: prologue syrk + 32-blocked factor/invert -------
// One 256-thread block per batch. Diag block arrives fully symmetric in global.
__device__ void potf_body(float* __restrict__ C, float* __restrict__ V,
                          int o, int last, int b) {
    int tid = threadIdx.x;
    float* A = C + (long)b * 1048576;
    float* Vp = V + (long)b * 8192;
    __shared__ float T[128][132];
    __shared__ float Li[4][32][33];     // diag-block inverses (full sq, zeros above)
    __shared__ float St[32][132];       // staging / trsm temp
    __shared__ float W[32][33];
    __shared__ float zs[128][9];
    int tx = tid & 15, ty = tid >> 4;
    // ---- load full symmetric 128x128 tile ----
    {
        int r = tid >> 1, c0 = (tid & 1) * 64;
        const float* src = A + (long)(o + r) * 1024 + o + c0;
#pragma unroll
        for (int k = 0; k < 16; k++) {
            float4 v = *(const float4*)(src + 4 * k);
            T[r][c0 + 4*k] = v.x; T[r][c0 + 4*k + 1] = v.y;
            T[r][c0 + 4*k + 2] = v.z; T[r][c0 + 4*k + 3] = v.w;
        }
    }
    __syncthreads();
    // ---- prologue (s>0): T -= Lp @ Lp^T, Lp = global block (o, o-128) ----
    if (o > 0) {
        float acc[8][8] = {};
        int lr = tid >> 1, lk = (tid & 1) * 16;
        for (int kc = 0; kc < 128; kc += 32) {
            const float* sp = A + (long)(o + lr) * 1024 + (o - 128) + kc + lk;
#pragma unroll
            for (int k4 = 0; k4 < 4; k4++) {
                float4 v = *(const float4*)(sp + 4 * k4);
                St[lk + 4*k4    ][lr] = v.x;
                St[lk + 4*k4 + 1][lr] = v.y;
                St[lk + 4*k4 + 2][lr] = v.z;
                St[lk + 4*k4 + 3][lr] = v.w;
            }
            __syncthreads();
#pragma unroll
            for (int k = 0; k < 32; k++) {
                float4 a0 = *(const float4*)&St[k][ty * 8];
                float4 a1 = *(const float4*)&St[k][ty * 8 + 4];
                float4 b0 = *(const float4*)&St[k][tx * 8];
                float4 b1 = *(const float4*)&St[k][tx * 8 + 4];
                float aa[8] = {a0.x,a0.y,a0.z,a0.w,a1.x,a1.y,a1.z,a1.w};
                float bb[8] = {b0.x,b0.y,b0.z,b0.w,b1.x,b1.y,b1.z,b1.w};
#pragma unroll
                for (int i = 0; i < 8; i++)
#pragma unroll
                    for (int j = 0; j < 8; j++) acc[i][j] += aa[i] * bb[j];
            }
            __syncthreads();
        }
#pragma unroll
        for (int i = 0; i < 8; i++)
#pragma unroll
            for (int j = 0; j < 8; j++)
                T[ty * 8 + i][tx * 8 + j] -= acc[i][j];
        __syncthreads();
    }
    // ---- 32-blocked Cholesky + diag inversion ----
    for (int d = 0; d < 4; d++) {
        int D = d * 32;
        if (tid < 32) {
            int j = tid;
            float a[32];
#pragma unroll
            for (int i = 0; i < 32; i++) a[i] = T[D + i][D + j];   // symmetric: a[i]=A[i][j]
            // right-looking Cholesky; lane j holds column j (mirrored storage:
            // post-factor a[i] = L[i][j] for i>=j, = L[j][i] for i<j)
#pragma unroll
            for (int i = 0; i < 32; i++) {
                float rs = rsqrtf(__shfl(a[i], i));
                float Lji = a[i] * rs;               // L[j][i] via symmetry (j>=i)
#pragma unroll
                for (int r = i + 1; r < 32; r++) {
                    float Lri = __shfl(a[r], i) * rs;
                    float upd = (j == i) ? Lri : (a[r] - Lri * Lji);
                    if (j >= i) a[r] = upd;
                }
                if (j >= i) a[i] = Lji;
            }
            // inversion: x = Linv column j (forward substitution, incremental sums)
            float x_[32];
            float acs[32];
#pragma unroll
            for (int i = 0; i < 32; i++) acs[i] = 0.0f;
#pragma unroll
            for (int k = 0; k < 32; k++) {
                float dk = __shfl(a[k], k);          // L[k][k]
                float xk;
                if (k == j)      xk = 1.0f / dk;
                else if (k > j)  xk = -acs[k] / dk;
                else             xk = 0.0f;
                x_[k] = xk;
#pragma unroll
                for (int i = k + 1; i < 32; i++)
                    acs[i] += __shfl(a[i], k) * xk;  // L[i][k] from lane k
            }
#pragma unroll
            for (int i = 0; i < 32; i++) Li[d][i][j] = x_[i];
        }
        __syncthreads();
        if (d < 3) {
            float* Sf = &St[0][0];
            int i0 = tid >> 3, j0 = (tid & 7) * 4;
            // trsm32: T(rb,d) <- T(rb,d) @ Linv_dd^T (via St temp; in-place hazard)
            for (int rb = d + 1; rb < 4; rb++) {
                float o0 = 0, o1 = 0, o2 = 0, o3 = 0;
#pragma unroll 8
                for (int k = 0; k < 32; k++) {
                    float av = T[rb * 32 + i0][D + k];
                    o0 += av * Li[d][j0    ][k];
                    o1 += av * Li[d][j0 + 1][k];
                    o2 += av * Li[d][j0 + 2][k];
                    o3 += av * Li[d][j0 + 3][k];
                }
                int base = (rb - d - 1) * 1024 + i0 * 32 + j0;
                Sf[base] = o0; Sf[base + 1] = o1; Sf[base + 2] = o2; Sf[base + 3] = o3;
            }
            __syncthreads();
            for (int rb = d + 1; rb < 4; rb++) {
                int base = (rb - d - 1) * 1024 + i0 * 32 + j0;
                T[rb * 32 + i0][D + j0    ] = Sf[base];
                T[rb * 32 + i0][D + j0 + 1] = Sf[base + 1];
                T[rb * 32 + i0][D + j0 + 2] = Sf[base + 2];
                T[rb * 32 + i0][D + j0 + 3] = Sf[base + 3];
            }
            __syncthreads();
            // syrk32 trailing, in-place (reads col d only; writes cols > d),
            // full-square so diag sub-blocks stay symmetric
            for (int pr = d + 1; pr < 4; pr++)
                for (int pc = d + 1; pc <= pr; pc++) {
                    float s0 = 0, s1 = 0, s2 = 0, s3 = 0;
#pragma unroll 8
                    for (int k = 0; k < 32; k++) {
                        float av = T[pr * 32 + i0][D + k];
                        s0 += av * T[pc * 32 + j0    ][D + k];
                        s1 += av * T[pc * 32 + j0 + 1][D + k];
                        s2 += av * T[pc * 32 + j0 + 2][D + k];
                        s3 += av * T[pc * 32 + j0 + 3][D + k];
                    }
                    T[pr * 32 + i0][pc * 32 + j0    ] -= s0;
                    T[pr * 32 + i0][pc * 32 + j0 + 1] -= s1;
                    T[pr * 32 + i0][pc * 32 + j0 + 2] -= s2;
                    T[pr * 32 + i0][pc * 32 + j0 + 3] -= s3;
                }
            __syncthreads();
        }
    }
    // ---- off-diagonal inverse blocks (column-major, in-place over L) ----
    int orr = tid >> 3;
    int oc = (tid & 7) * 4;
    for (int j = 0; j < 3; j++) {
        for (int i = j + 1; i < 4; i++) {
            float w0 = 0, w1 = 0, w2 = 0, w3 = 0;
#pragma unroll 8
            for (int kk = 0; kk < 32; kk++) {      // kb == j: L_ij @ Linv_jj
                float l = T[i * 32 + orr][j * 32 + kk];
                w0 += l * Li[j][kk][oc    ];
                w1 += l * Li[j][kk][oc + 1];
                w2 += l * Li[j][kk][oc + 2];
                w3 += l * Li[j][kk][oc + 3];
            }
            for (int kb = j + 1; kb < i; kb++) {
#pragma unroll 8
                for (int kk = 0; kk < 32; kk++) {
                    float l = T[i * 32 + orr][kb * 32 + kk];
                    w0 += l * T[kb * 32 + kk][j * 32 + oc    ];
                    w1 += l * T[kb * 32 + kk][j * 32 + oc + 1];
                    w2 += l * T[kb * 32 + kk][j * 32 + oc + 2];
                    w3 += l * T[kb * 32 + kk][j * 32 + oc + 3];
                }
            }
            W[orr][oc] = w0; W[orr][oc+1] = w1; W[orr][oc+2] = w2; W[orr][oc+3] = w3;
            __syncthreads();
            float v0 = 0, v1 = 0, v2 = 0, v3 = 0;
#pragma unroll 8
            for (int kk = 0; kk < 32; kk++) {
                float l = Li[i][orr][kk];
                v0 += l * W[kk][oc    ];
                v1 += l * W[kk][oc + 1];
                v2 += l * W[kk][oc + 2];
                v3 += l * W[kk][oc + 3];
            }
            __syncthreads();
            T[i * 32 + orr][j * 32 + oc    ] = -v0;
            T[i * 32 + orr][j * 32 + oc + 1] = -v1;
            T[i * 32 + orr][j * 32 + oc + 2] = -v2;
            T[i * 32 + orr][j * 32 + oc + 3] = -v3;
            __syncthreads();
        }
    }
    // ---- place diag inverses into T, zero strict upper ----
    {
        int r = tid >> 1, c0 = (tid & 1) * 64;
        int rb = r >> 5, ri = r & 31;
#pragma unroll
        for (int k = 0; k < 64; k++) {
            int c = c0 + k, cb = c >> 5;
            if (cb == rb)      T[r][c] = Li[rb][ri][c & 31];
            else if (cb > rb)  T[r][c] = 0.0f;
        }
    }
    __syncthreads();
    // ---- writeback Linv (exact zeros above diagonal) ----
    {
        int r = tid >> 1, c0 = (tid & 1) * 64;
        float* dst = A + (long)(o + r) * 1024 + o + c0;
#pragma unroll
        for (int k = 0; k < 16; k++) {
            int c = c0 + 4 * k;
            float4 v = make_float4(T[r][c], T[r][c + 1], T[r][c + 2], T[r][c + 3]);
            *(float4*)(dst + 4 * k) = v;
        }
    }
    // ---- forward diag step: y = Linv @ z; last block also x = Linv^T y ----
    {
        int k = tid >> 1, c0 = (tid & 1) * 4;
        float4 v = *(const float4*)&Vp[(o + k) * 8 + c0];
        zs[k][c0] = v.x; zs[k][c0 + 1] = v.y; zs[k][c0 + 2] = v.z; zs[k][c0 + 3] = v.w;
    }
    __syncthreads();
    {
        int r = tid & 127, c0 = (tid >> 7) * 4;
        float y0 = 0, y1 = 0, y2 = 0, y3 = 0;
#pragma unroll 8
        for (int k = 0; k < 128; k++) {
            float l = T[r][k];
            y0 += l * zs[k][c0    ];
            y1 += l * zs[k][c0 + 1];
            y2 += l * zs[k][c0 + 2];
            y3 += l * zs[k][c0 + 3];
        }
        if (!last) {
            *(float4*)&Vp[(o + r) * 8 + c0] = make_float4(y0, y1, y2, y3);
        } else {
            __syncthreads();
            zs[r][c0] = y0; zs[r][c0+1] = y1; zs[r][c0+2] = y2; zs[r][c0+3] = y3;
            __syncthreads();
            float x0 = 0, x1 = 0, x2 = 0, x3 = 0;
#pragma unroll 8
            for (int k = 0; k < 128; k++) {
                float l = T[k][r];
                x0 += l * zs[k][c0    ];
                x1 += l * zs[k][c0 + 1];
                x2 += l * zs[k][c0 + 2];
                x3 += l * zs[k][c0 + 3];
            }
            *(float4*)&Vp[(o + r) * 8 + c0] = make_float4(x0, x1, x2, x3);
        }
    }
}

// ---------------- syrk body: A(bi,bj) -= L21_i @ L21_j^T -----------------------
// Diag pairs write FULL SQUARE (keeps future potf diag blocks symmetric).
__device__ void syrk_body(float* __restrict__ C, int o, int pti, int ptj, int b) {
    float* A = C + (long)b * 1048576;
    int bi = o + 128 + pti * 128, bj = o + 128 + ptj * 128;
    __shared__ float As[32][132];
    __shared__ float Bs[32][132];
    int tid = threadIdx.x;
    int tx = tid & 15, ty = tid >> 4;
    float acc[8][8] = {};
    int lr = tid >> 1;
    int lk = (tid & 1) * 16;
    bool diag = (bi == bj);
    for (int kc = 0; kc < 128; kc += 32) {
        {
            const float* src = A + (long)(bi + lr) * 1024 + o + kc + lk;
#pragma unroll
            for (int k4 = 0; k4 < 4; k4++) {
                float4 v = *(const float4*)(src + 4 * k4);
                As[lk + 4*k4    ][lr] = v.x;
                As[lk + 4*k4 + 1][lr] = v.y;
                As[lk + 4*k4 + 2][lr] = v.z;
                As[lk + 4*k4 + 3][lr] = v.w;
            }
            if (!diag) {
                const float* sb = A + (long)(bj + lr) * 1024 + o + kc + lk;
#pragma unroll
                for (int k4 = 0; k4 < 4; k4++) {
                    float4 v = *(const float4*)(sb + 4 * k4);
                    Bs[lk + 4*k4    ][lr] = v.x;
                    Bs[lk + 4*k4 + 1][lr] = v.y;
                    Bs[lk + 4*k4 + 2][lr] = v.z;
                    Bs[lk + 4*k4 + 3][lr] = v.w;
                }
            }
        }
        __syncthreads();
        {
            const float (*Bp)[132] = diag ? As : Bs;
#pragma unroll
            for (int k = 0; k < 32; k++) {
                float4 a0 = *(const float4*)&As[k][ty * 8];
                float4 a1 = *(const float4*)&As[k][ty * 8 + 4];
                float4 b0 = *(const float4*)&Bp[k][tx * 8];
                float4 b1 = *(const float4*)&Bp[k][tx * 8 + 4];
                float aa[8] = {a0.x,a0.y,a0.z,a0.w,a1.x,a1.y,a1.z,a1.w};
                float bb[8] = {b0.x,b0.y,b0.z,b0.w,b1.x,b1.y,b1.z,b1.w};
#pragma unroll
                for (int i = 0; i < 8; i++)
#pragma unroll
                    for (int j = 0; j < 8; j++) acc[i][j] += aa[i] * bb[j];
            }
        }
        __syncthreads();
    }
#pragma unroll
    for (int i = 0; i < 8; i++) {
        int r = bi + ty * 8 + i;
        float* dst = A + (long)r * 1024 + bj + tx * 8;
        float4 p0 = *(const float4*)dst;
        float4 p1 = *(const float4*)(dst + 4);
        p0.x -= acc[i][0]; p0.y -= acc[i][1]; p0.z -= acc[i][2]; p0.w -= acc[i][3];
        p1.x -= acc[i][4]; p1.y -= acc[i][5]; p1.z -= acc[i][6]; p1.w -= acc[i][7];
        *(float4*)dst = p0;
        *(float4*)(dst + 4) = p1;
    }
}

// ---------------- fused launch: potf(s) [blocks 0-15] + ALL syrk(s-1) pairs
// except (0,0) (handled by potf's prologue) ------------------------------------
__global__ __launch_bounds__(256) void k_potf_syrk(float* __restrict__ C,
                                                   float* __restrict__ V,
                                                   int o, int last) {
    int bx = blockIdx.x;
    if (bx < 16) {
        potf_body(C, V, o, last, bx);
    } else {
        int v = bx - 16;
        int bb = v & 15;
        int p = (v >> 4) + 1;             // skip pair (0,0)
        int tii = row_of(p);
        int tjj = p - tii * (tii + 1) / 2;
        syrk_body(C, o - 128, tii, tjj, bb);
    }
}

// ---------------- TRSM-GEMM + fwd z-update -------------------------------------
__global__ __launch_bounds__(256) void k_trsmg(float* __restrict__ C,
                                               float* __restrict__ V, int o) {
    int b = blockIdx.y;
    float* A = C + (long)b * 1048576;
    float* Vp = V + (long)b * 8192;
    int bi = o + 128 + blockIdx.x * 128;
    const float* Linv = A + (long)o * 1024 + o;
    __shared__ float As[32][132];
    __shared__ float Ls[32][132];   // reused as ys (flat) in the tail
    int tid = threadIdx.x;
    int tx = tid & 15, ty = tid >> 4;
    float acc[8][8] = {};
    int lr = tid >> 1;
    int lk = (tid & 1) * 16;
    for (int kc = 0; kc < 128; kc += 32) {
        const float* src = A + (long)(bi + lr) * 1024 + o + kc + lk;
        const float* sl  = Linv + (long)lr * 1024 + kc + lk;
#pragma unroll
        for (int k4 = 0; k4 < 4; k4++) {
            float4 v = *(const float4*)(src + 4 * k4);
            As[lk + 4*k4    ][lr] = v.x;
            As[lk + 4*k4 + 1][lr] = v.y;
            As[lk + 4*k4 + 2][lr] = v.z;
            As[lk + 4*k4 + 3][lr] = v.w;
            float4 w = *(const float4*)(sl + 4 * k4);
            Ls[lk + 4*k4    ][lr] = w.x;
            Ls[lk + 4*k4 + 1][lr] = w.y;
            Ls[lk + 4*k4 + 2][lr] = w.z;
            Ls[lk + 4*k4 + 3][lr] = w.w;
        }
        __syncthreads();
#pragma unroll
        for (int k = 0; k < 32; k++) {
            float4 a0 = *(const float4*)&As[k][ty * 8];
            float4 a1 = *(const float4*)&As[k][ty * 8 + 4];
            float4 b0 = *(const float4*)&Ls[k][tx * 8];
            float4 b1 = *(const float4*)&Ls[k][tx * 8 + 4];
            float aa[8] = {a0.x,a0.y,a0.z,a0.w,a1.x,a1.y,a1.z,a1.w};
            float bb[8] = {b0.x,b0.y,b0.z,b0.w,b1.x,b1.y,b1.z,b1.w};
#pragma unroll
            for (int i = 0; i < 8; i++)
#pragma unroll
                for (int j = 0; j < 8; j++) acc[i][j] += aa[i] * bb[j];
        }
        __syncthreads();
    }
#pragma unroll
    for (int i = 0; i < 8; i++) {
        float* dst = A + (long)(bi + ty * 8 + i) * 1024 + o + tx * 8;
        *(float4*)dst       = make_float4(acc[i][0], acc[i][1], acc[i][2], acc[i][3]);
        *(float4*)(dst + 4) = make_float4(acc[i][4], acc[i][5], acc[i][6], acc[i][7]);
    }
    // tail: z_j -= L21 @ y_s (acc registers ARE L21; stream via LDS chunks)
    float* ysf = &Ls[0][0];
    {
        int k = tid >> 1, c0 = (tid & 1) * 4;
        float4 v = *(const float4*)&Vp[(o + k) * 8 + c0];
        ysf[k * 9 + c0] = v.x; ysf[k * 9 + c0 + 1] = v.y;
        ysf[k * 9 + c0 + 2] = v.z; ysf[k * 9 + c0 + 3] = v.w;
    }
    __syncthreads();
    float zacc0 = 0, zacc1 = 0, zacc2 = 0, zacc3 = 0;
    int zr = tid & 127, zc0 = (tid >> 7) * 4;
#pragma unroll
    for (int ch = 0; ch < 4; ch++) {
        if ((tx >> 2) == ch) {
            int cb = (tx & 3) * 8;
#pragma unroll
            for (int j = 0; j < 8; j++)
#pragma unroll
                for (int i = 0; i < 8; i++)
                    As[cb + j][ty * 8 + i] = acc[i][j];
        }
        __syncthreads();
#pragma unroll 8
        for (int k = 0; k < 32; k++) {
            float l = As[k][zr];
            const float* yp = &ysf[(ch * 32 + k) * 9 + zc0];
            zacc0 += l * yp[0]; zacc1 += l * yp[1];
            zacc2 += l * yp[2]; zacc3 += l * yp[3];
        }
        __syncthreads();
    }
    float* vp = &Vp[(bi + zr) * 8 + zc0];
    float4 old = *(const float4*)vp;
    old.x -= zacc0; old.y -= zacc1; old.z -= zacc2; old.w -= zacc3;
    *(float4*)vp = old;
}

// ---------------- backward step k: y_j -= L_{k,j}^T x_k (j<k, parallel) --------
__global__ __launch_bounds__(256) void k_bstep(const float* __restrict__ C,
                                               float* __restrict__ V, int k) {
    int b = blockIdx.y, j = blockIdx.x, tid = threadIdx.x;
    const float* A = C + (long)b * 1048576;
    float* Vp = V + (long)b * 8192;
    __shared__ float Lb[128][129];
    __shared__ float xs[128][9];
    __shared__ float ys[128][9];
    {
        int kk = tid >> 1, c0 = (tid & 1) * 4;
        float4 v = *(const float4*)&Vp[(k * 128 + kk) * 8 + c0];
        xs[kk][c0] = v.x; xs[kk][c0+1] = v.y; xs[kk][c0+2] = v.z; xs[kk][c0+3] = v.w;
    }
#pragma unroll
    for (int m = 0; m < 16; m++) {
        int e = tid + m * 256;
        int i = e >> 5, j4 = (e & 31) * 4;
        float4 v = *(const float4*)&A[(long)(k * 128 + i) * 1024 + j * 128 + j4];
        Lb[i][j4] = v.x; Lb[i][j4+1] = v.y; Lb[i][j4+2] = v.z; Lb[i][j4+3] = v.w;
    }
    __syncthreads();
    int r = tid & 127, c0 = (tid >> 7) * 4;
    float u0 = 0, u1 = 0, u2 = 0, u3 = 0;
#pragma unroll 8
    for (int kk = 0; kk < 128; kk++) {
        float l = Lb[kk][r];
        u0 += l * xs[kk][c0    ];
        u1 += l * xs[kk][c0 + 1];
        u2 += l * xs[kk][c0 + 2];
        u3 += l * xs[kk][c0 + 3];
    }
    float* vp = &Vp[(j * 128 + r) * 8 + c0];
    float4 old = *(const float4*)vp;
    old.x -= u0; old.y -= u1; old.z -= u2; old.w -= u3;
    if (j < k - 1) {
        *(float4*)vp = old;
    } else {
        ys[r][c0] = old.x; ys[r][c0+1] = old.y; ys[r][c0+2] = old.z; ys[r][c0+3] = old.w;
        __syncthreads();
        int o = j * 128;
#pragma unroll
        for (int m = 0; m < 16; m++) {
            int e = tid + m * 256;
            int i = e >> 5, j4 = (e & 31) * 4;
            float4 v = *(const float4*)&A[(long)(o + i) * 1024 + o + j4];
            Lb[i][j4] = v.x; Lb[i][j4+1] = v.y; Lb[i][j4+2] = v.z; Lb[i][j4+3] = v.w;
        }
        __syncthreads();
        float x0 = 0, x1 = 0, x2 = 0, x3 = 0;
#pragma unroll 8
        for (int kk = 0; kk < 128; kk++) {
            float l = Lb[kk][r];
            x0 += l * ys[kk][c0    ];
            x1 += l * ys[kk][c0 + 1];
            x2 += l * ys[kk][c0 + 2];
            x3 += l * ys[kk][c0 + 3];
        }
        *(float4*)vp = make_float4(x0, x1, x2, x3);
    }
}

// ---------------- fused output: out[q,:] = sum_k exp(-d(Qs_q,Ks_k)) X[k,:] -----
__global__ void k_out(const float* __restrict__ Qs, const float* __restrict__ Ks,
                      const float* __restrict__ X, float* __restrict__ out) {
    int b = blockIdx.x >> 4;
    int qc = blockIdx.x & 15;
    int t = threadIdx.x;
    int q = t & 63, ks = t >> 6;
    __shared__ float kx[1024][3];
    __shared__ __align__(16) float xv[1024][8];
    __shared__ float red[4][64][8];
    for (int i = t; i < 3072; i += 256) kx[i / 3][i % 3] = Ks[b * 3072 + i];
    for (int i = t; i < 8192; i += 256) xv[i >> 3][i & 7] = X[b * 8192 + i];
    __syncthreads();
    int gq = b * 1024 + qc * 64 + q;
    const float* qp = Qs + (long)gq * 3;
    float qx = qp[0], qy = qp[1], qz = qp[2];
    float acc[8] = {};
    int k0 = ks * 256;
#pragma unroll 2
    for (int k = k0; k < k0 + 256; k++) {
        float dx = qx - kx[k][0], dy = qy - kx[k][1], dz = qz - kx[k][2];
        float w = __expf(-sqrtf(dx * dx + dy * dy + dz * dz + 1e-12f));
        float4 xa = *(const float4*)&xv[k][0];
        float4 xb = *(const float4*)&xv[k][4];
        acc[0] += w * xa.x; acc[1] += w * xa.y; acc[2] += w * xa.z; acc[3] += w * xa.w;
        acc[4] += w * xb.x; acc[5] += w * xb.y; acc[6] += w * xb.z; acc[7] += w * xb.w;
    }
#pragma unroll
    for (int c = 0; c < 8; c++) red[ks][q][c] = acc[c];
    __syncthreads();
    if (ks == 0) {
        float* op = out + (long)gq * 8;
#pragma unroll
        for (int c = 0; c < 8; c++)
            op[c] = red[0][q][c] + red[1][q][c] + red[2][q][c] + red[3][q][c];
    }
}

extern "C" void kernel_launch(void* const* d_in, const int* in_sizes, int n_in,
                              void* d_out, int out_size, void* d_ws, size_t ws_size,
                              hipStream_t stream) {
    const float* KEY   = (const float*)d_in[0];
    const float* VALUE = (const float*)d_in[1];
    const float* QUERY = (const float*)d_in[2];
    const float* W1w = (const float*)d_in[3];  const float* W1b = (const float*)d_in[4];
    const float* W2w = (const float*)d_in[5];  const float* W2b = (const float*)d_in[6];
    const float* W3w = (const float*)d_in[7];  const float* W3b = (const float*)d_in[8];
    const float* Wv1w = (const float*)d_in[9]; const float* Wv1b = (const float*)d_in[10];
    const float* Wv2w = (const float*)d_in[11];const float* Wv2b = (const float*)d_in[12];
    const float* Wv3w = (const float*)d_in[13];const float* Wv3b = (const float*)d_in[14];

    float* ws  = (float*)d_ws;
    float* C    = ws;                 // 16*1024*1024
    float* Ks   = C + 16777216;       // 16*1024*3
    float* Qs   = Ks + 49152;
    float* Vs   = Qs + 49152;         // 16*1024*8 (z -> y -> x in place)
    float* W2T  = Vs + 131072;
    float* Wv2T = W2T + 16384;

    float* out = (float*)d_out;

    hipLaunchKernelGGL(k_transpose, dim3(128), dim3(256), 0, stream, W2w, Wv2w, W2T, Wv2T);
    hipLaunchKernelGGL(k_mlp_kq, dim3(1024), dim3(128), 0, stream,
                       KEY, Ks, QUERY, Qs, W1w, W1b, W2T, W2b, W3w, W3b);
    hipLaunchKernelGGL(k_mlp_v, dim3(1024), dim3(128), 0, stream,
                       VALUE, Vs, Wv1w, Wv1b, Wv2T, Wv2b, Wv3w, Wv3b);
    hipLaunchKernelGGL(k_buildC, dim3(65536), dim3(256), 0, stream, Ks, C);

    // factorization + fused forward substitution: 2 launches per step
    for (int s = 0; s < 8; s++) {
        int o = s * 128;
        int nt_prev = 8 - s;                        // trailing count of step s-1
        int np = (s >= 1) ? (nt_prev * (nt_prev + 1)) / 2 - 1 : 0;
        hipLaunchKernelGGL(k_potf_syrk, dim3(16 + np * 16), dim3(256), 0, stream,
                           C, Vs, o, (s == 7) ? 1 : 0);
        int nt = 7 - s;
        if (nt > 0)
            hipLaunchKernelGGL(k_trsmg, dim3(nt, 16), dim3(256), 0, stream, C, Vs, o);
    }
    // backward substitution: parallel right-looking (x_7 done inside last potf)
    for (int k = 7; k >= 1; k--)
        hipLaunchKernelGGL(k_bstep, dim3(k, 16), dim3(256), 0, stream, C, Vs, k);

    hipLaunchKernelGGL(k_out, dim3(256), dim3(256), 0, stream, Qs, Ks, Vs, out);
}

// Round 13
// 1139.107 us; speedup vs baseline: 1.5300x; 1.5300x over previous
//
#include <hip/hip_runtime.h>
#include <hip/hip_bf16.h>

// krignn2: out = C_qk @ inv(C_kk) @ (VALUE*mlp_v(VALUE))
// C_kk = exp(-cdist(Ks,Ks)) + 1e-3 I,  Ks = KEY*mlp(KEY), Qs = QUERY*mlp(QUERY).
// Blocked fp32 Cholesky + inverted diag blocks + fused fwd/parallel bwd solve.
// R13: R12's 32-blocked potf core REVERTED (168us vs 76us — serial shfl chain +
//      scalar-LDS trsm32/syrk32). potf core = R10/R11 register-tile version
//      (proven 76us). Kept from R12: schedule only — potf(s) prologue applies
//      the (0,0) syrk (T -= Lp Lp^T, LDS-staged, register tiles); all other
//      syrk(s-1) pairs (incl. (ti>0,0)) ride potf_syrk(s). syrkc deleted.
//      27 dispatches. syrk_body diag writes guarded (R11 form).

__device__ __forceinline__ int row_of(int e) {
    int i = (int)((sqrtf(8.0f * (float)e + 1.0f) - 1.0f) * 0.5f);
    while ((i + 1) * (i + 2) / 2 <= e) i++;
    while (i * (i + 1) / 2 > e) i--;
    return i;
}

// ---------------- transpose W2 / Wv2 (for coalesced layer-2 reads) -------------
__global__ void k_transpose(const float* __restrict__ W2, const float* __restrict__ Wv2,
                            float* __restrict__ W2T, float* __restrict__ Wv2T) {
    int tid = blockIdx.x * 256 + threadIdx.x;   // 0..32767
    int e = tid & 16383;
    int r = e >> 7, c = e & 127;
    if (tid < 16384) W2T[c * 128 + r] = W2[e];
    else             Wv2T[c * 128 + r] = Wv2[e];
}

// ---------------- MLP body (Linear->ReLU->Linear->ReLU->Linear) + scale --------
template<int DI, int P>
__device__ __forceinline__ void mlp_body(const float* __restrict__ in,
                                         float* __restrict__ out, int base,
                                         const float* __restrict__ W1,
                                         const float* __restrict__ b1,
                                         const float* __restrict__ W2T,
                                         const float* __restrict__ b2,
                                         const float* __restrict__ W3,
                                         const float* __restrict__ b3) {
    __shared__ float xs[P][DI];
    __shared__ float h1[P][128];
    __shared__ float h2[P][129];
    int t = threadIdx.x;
    for (int i = t; i < P * DI; i += 128) xs[i / DI][i % DI] = in[base * DI + i];
    __syncthreads();
    float w1r[DI];
#pragma unroll
    for (int d = 0; d < DI; d++) w1r[d] = W1[t * DI + d];
    float b1t = b1[t], b2t = b2[t];
#pragma unroll
    for (int p = 0; p < P; p++) {
        float s = b1t;
#pragma unroll
        for (int d = 0; d < DI; d++) s += w1r[d] * xs[p][d];
        h1[p][t] = fmaxf(s, 0.0f);
    }
    __syncthreads();
    float acc[P];
#pragma unroll
    for (int p = 0; p < P; p++) acc[p] = b2t;
    for (int k = 0; k < 128; k++) {
        float w = W2T[k * 128 + t];
#pragma unroll
        for (int p = 0; p < P; p++) acc[p] += w * h1[p][k];
    }
#pragma unroll
    for (int p = 0; p < P; p++) h2[p][t] = fmaxf(acc[p], 0.0f);
    __syncthreads();
    if (t < P * DI) {
        int p = t / DI, d = t % DI;
        float s = b3[d];
        for (int k = 0; k < 128; k++) s += W3[d * 128 + k] * h2[p][k];
        int gi = base * DI + t;
        out[gi] = in[gi] * s;
    }
}

__global__ void k_mlp_kq(const float* __restrict__ KEY, float* __restrict__ Ks,
                         const float* __restrict__ QUERY, float* __restrict__ Qs,
                         const float* __restrict__ W1, const float* __restrict__ b1,
                         const float* __restrict__ W2T, const float* __restrict__ b2,
                         const float* __restrict__ W3, const float* __restrict__ b3) {
    if (blockIdx.x < 512)
        mlp_body<3, 32>(KEY, Ks, blockIdx.x * 32, W1, b1, W2T, b2, W3, b3);
    else
        mlp_body<3, 32>(QUERY, Qs, (blockIdx.x - 512) * 32, W1, b1, W2T, b2, W3, b3);
}

__global__ void k_mlp_v(const float* __restrict__ VALUE, float* __restrict__ Vs,
                        const float* __restrict__ W1, const float* __restrict__ b1,
                        const float* __restrict__ W2T, const float* __restrict__ b2,
                        const float* __restrict__ W3, const float* __restrict__ b3) {
    mlp_body<8, 16>(VALUE, Vs, blockIdx.x * 16, W1, b1, W2T, b2, W3, b3);
}

// ---------------- build C_kk = exp(-dist) + nugget*I ---------------------------
__global__ void k_buildC(const float* __restrict__ Ks, float* __restrict__ C) {
    long idx = (long)blockIdx.x * 256 + threadIdx.x;  // 16M elements
    int b = (int)(idx >> 20);
    int rem = (int)(idx & 1048575);
    int i = rem >> 10, j = rem & 1023;
    const float* a = Ks + ((long)b * 1024 + i) * 3;
    const float* bb = Ks + ((long)b * 1024 + j) * 3;
    float d0 = a[0] - bb[0], d1 = a[1] - bb[1], d2 = a[2] - bb[2];
    float dist = sqrtf(d0 * d0 + d1 * d1 + d2 * d2 + 1e-12f);
    float v = __expf(-dist);
    if (i == j) v += 1e-3f;
    C[idx] = v;
}

// ---------------- potf body (R10 register-tile core) + prologue syrk -----------
// grid-block per batch, 256 threads. thread t<136 owns 8x8 lower-tri tile
// (ti,tj). Prologue (o>0): Treg -= Lp@Lp^T with Lp rows LDS-staged k-major.
// Then: 16 rank-8 LDL panels (owners stage -> wave0 shfl -> register trailing),
// dump to LDS, convert to Cholesky (zero upper), blocked trtri, write Linv_ii,
// y = Linv@z (+ x = Linv^T y on last).
__device__ void potf_body(float* __restrict__ C, float* __restrict__ V,
                          int o, int last, int b) {
    int tid = threadIdx.x;
    float* A = C + (long)b * 1048576;
    float* Vp = V + (long)b * 8192;
    __shared__ float T[128][132];
    __shared__ __align__(16) float cv[128][8];
    __shared__ __align__(16) float cw[128][8];
    __shared__ __align__(16) float Pn[128][8];
    __shared__ __align__(16) float St[32][132];
    __shared__ float rsd[128];
    __shared__ float W[32][33];
    __shared__ float zs[128][9];
    bool active = (tid < 136);
    int ti = 0, tj = 0;
    if (active) { ti = row_of(tid); tj = tid - ti * (ti + 1) / 2; }
    int r0 = ti * 8, c0t = tj * 8;
    float Treg[8][8];
    if (active) {
        const float* src = A + (long)(o + r0) * 1024 + o + c0t;
#pragma unroll
        for (int i = 0; i < 8; i++) {
            float4 va = *(const float4*)(src + (long)i * 1024);
            float4 vb = *(const float4*)(src + (long)i * 1024 + 4);
            Treg[i][0] = va.x; Treg[i][1] = va.y; Treg[i][2] = va.z; Treg[i][3] = va.w;
            Treg[i][4] = vb.x; Treg[i][5] = vb.y; Treg[i][6] = vb.z; Treg[i][7] = vb.w;
        }
    }
    int lane = tid & 63;
    __syncthreads();
    // ---- prologue: Treg -= Lp @ Lp^T  (Lp = global block (o, o-128)) ----
    if (o > 0) {
        for (int kc = 0; kc < 4; kc++) {
            {
                int r = tid >> 1, lk = (tid & 1) * 16;
                const float* sp = A + (long)(o + r) * 1024 + (o - 128) + kc * 32 + lk;
#pragma unroll
                for (int k4 = 0; k4 < 4; k4++) {
                    float4 v = *(const float4*)(sp + 4 * k4);
                    St[lk + 4*k4    ][r] = v.x;
                    St[lk + 4*k4 + 1][r] = v.y;
                    St[lk + 4*k4 + 2][r] = v.z;
                    St[lk + 4*k4 + 3][r] = v.w;
                }
            }
            __syncthreads();
            if (active) {
#pragma unroll 4
                for (int k = 0; k < 32; k++) {
                    float4 a0 = *(const float4*)&St[k][r0];
                    float4 a1 = *(const float4*)&St[k][r0 + 4];
                    float4 b0 = *(const float4*)&St[k][c0t];
                    float4 b1 = *(const float4*)&St[k][c0t + 4];
                    float aa[8] = {a0.x,a0.y,a0.z,a0.w,a1.x,a1.y,a1.z,a1.w};
                    float bb[8] = {b0.x,b0.y,b0.z,b0.w,b1.x,b1.y,b1.z,b1.w};
#pragma unroll
                    for (int i = 0; i < 8; i++)
#pragma unroll
                        for (int j = 0; j < 8; j++) Treg[i][j] -= aa[i] * bb[j];
                }
            }
            __syncthreads();
        }
    }
    // ---- 16 rank-8 panels ----
    for (int jbt = 0; jbt < 16; jbt++) {
        int jb = jbt * 8;
        if (active && tj == jbt) {
#pragma unroll
            for (int i = 0; i < 8; i++) {
                *(float4*)&Pn[r0 + i][0] = make_float4(Treg[i][0], Treg[i][1], Treg[i][2], Treg[i][3]);
                *(float4*)&Pn[r0 + i][4] = make_float4(Treg[i][4], Treg[i][5], Treg[i][6], Treg[i][7]);
            }
        }
        __syncthreads();
        if (tid < 64) {
            int r1 = lane, r2 = 64 + lane;
            float v1[8], v2[8], w1[8], w2[8];
#pragma unroll
            for (int q = 0; q < 8; q++) {
                int j = jb + q;
                int jl = j & 63;
                bool hi = (j >= 64);
                float a1 = Pn[r1][q], a2 = Pn[r2][q];
#pragma unroll
                for (int p = 0; p < 8; p++) {
                    if (p < q) {
                        float wj = __shfl(hi ? w2[p] : w1[p], jl);
                        a1 -= v1[p] * wj;
                        a2 -= v2[p] * wj;
                    }
                }
                v1[q] = a1; v2[q] = a2;
                float dj = __shfl(hi ? a2 : a1, jl);
                float dinv = 1.0f / dj;
                w1[q] = a1 * dinv; w2[q] = a2 * dinv;
            }
            *(float4*)&cv[r1][0] = make_float4(v1[0], v1[1], v1[2], v1[3]);
            *(float4*)&cv[r1][4] = make_float4(v1[4], v1[5], v1[6], v1[7]);
            *(float4*)&cv[r2][0] = make_float4(v2[0], v2[1], v2[2], v2[3]);
            *(float4*)&cv[r2][4] = make_float4(v2[4], v2[5], v2[6], v2[7]);
            *(float4*)&cw[r1][0] = make_float4(w1[0], w1[1], w1[2], w1[3]);
            *(float4*)&cw[r1][4] = make_float4(w1[4], w1[5], w1[6], w1[7]);
            *(float4*)&cw[r2][0] = make_float4(w2[0], w2[1], w2[2], w2[3]);
            *(float4*)&cw[r2][4] = make_float4(w2[4], w2[5], w2[6], w2[7]);
        }
        __syncthreads();
        if (active && tj == jbt) {
#pragma unroll
            for (int i = 0; i < 8; i++) {
                float4 va = *(const float4*)&cv[r0 + i][0];
                float4 vb = *(const float4*)&cv[r0 + i][4];
                Treg[i][0] = va.x; Treg[i][1] = va.y; Treg[i][2] = va.z; Treg[i][3] = va.w;
                Treg[i][4] = vb.x; Treg[i][5] = vb.y; Treg[i][6] = vb.z; Treg[i][7] = vb.w;
            }
        } else if (active && tj > jbt) {
#pragma unroll
            for (int h = 0; h < 2; h++) {
                float va4[8][4], wb4[8][4];
#pragma unroll
                for (int i = 0; i < 8; i++) {
                    float4 v = *(const float4*)&cv[r0 + i][h * 4];
                    va4[i][0] = v.x; va4[i][1] = v.y; va4[i][2] = v.z; va4[i][3] = v.w;
                }
#pragma unroll
                for (int j = 0; j < 8; j++) {
                    float4 v = *(const float4*)&cw[c0t + j][h * 4];
                    wb4[j][0] = v.x; wb4[j][1] = v.y; wb4[j][2] = v.z; wb4[j][3] = v.w;
                }
#pragma unroll
                for (int i = 0; i < 8; i++)
#pragma unroll
                    for (int j = 0; j < 8; j++)
                        Treg[i][j] -= va4[i][0] * wb4[j][0] + va4[i][1] * wb4[j][1]
                                    + va4[i][2] * wb4[j][2] + va4[i][3] * wb4[j][3];
            }
        }
        __syncthreads();
    }
    // ---- dump registers (raw LDL lower) to LDS T ----
    if (active) {
#pragma unroll
        for (int i = 0; i < 8; i++) {
            *(float4*)&T[r0 + i][c0t]     = make_float4(Treg[i][0], Treg[i][1], Treg[i][2], Treg[i][3]);
            *(float4*)&T[r0 + i][c0t + 4] = make_float4(Treg[i][4], Treg[i][5], Treg[i][6], Treg[i][7]);
        }
    }
    __syncthreads();
    int rg = tid >> 4;
    int cg = tid & 15;
    int wv = tid >> 6;
    // ---- LDL -> Cholesky L; ZERO upper half ----
    if (tid < 128) rsd[tid] = rsqrtf(T[tid][tid]);
    __syncthreads();
#pragma unroll
    for (int j = 0; j < 8; j++) {
        int c = cg + 16 * j;
#pragma unroll
        for (int i = 0; i < 8; i++) {
            int r = rg * 8 + i;
            if (c <= r) T[r][c] *= rsd[c];
            else        T[r][c] = 0.0f;
        }
    }
    __syncthreads();
    // ---- trtri phase 2: 4 waves invert the 32x32 diagonal sub-blocks ----
    if (lane < 32) {
        int d0 = wv * 32;
        int j = lane;
        float x[32];
#pragma unroll
        for (int i = 0; i < 32; i++) {
            float dinv = 1.0f / T[d0 + i][d0 + i];
            float s = 0.0f;
#pragma unroll
            for (int k = 0; k < i; k++) s += T[d0 + i][d0 + k] * x[k];
            x[i] = (i == j) ? dinv : -s * dinv;
        }
#pragma unroll
        for (int i = 0; i < 32; i++) T[d0 + i][d0 + j] = x[i];
    }
    __syncthreads();
    // ---- trtri phase 3: off-diagonal sub-blocks, column-major in-place ----
    int orr = tid >> 3;
    int oc = (tid & 7) * 4;
    for (int j = 0; j < 3; j++) {
        for (int i = j + 1; i < 4; i++) {
            float w0 = 0, w1 = 0, w2 = 0, w3 = 0;
            for (int kb = j; kb < i; kb++) {
#pragma unroll 8
                for (int kk = 0; kk < 32; kk++) {
                    float l = T[i * 32 + orr][kb * 32 + kk];
                    w0 += l * T[kb * 32 + kk][j * 32 + oc    ];
                    w1 += l * T[kb * 32 + kk][j * 32 + oc + 1];
                    w2 += l * T[kb * 32 + kk][j * 32 + oc + 2];
                    w3 += l * T[kb * 32 + kk][j * 32 + oc + 3];
                }
            }
            W[orr][oc] = w0; W[orr][oc+1] = w1; W[orr][oc+2] = w2; W[orr][oc+3] = w3;
            __syncthreads();
            float v0 = 0, v1 = 0, v2 = 0, v3 = 0;
#pragma unroll 8
            for (int kk = 0; kk < 32; kk++) {
                float l = T[i * 32 + orr][i * 32 + kk];
                v0 += l * W[kk][oc    ];
                v1 += l * W[kk][oc + 1];
                v2 += l * W[kk][oc + 2];
                v3 += l * W[kk][oc + 3];
            }
            __syncthreads();
            T[i * 32 + orr][j * 32 + oc    ] = -v0;
            T[i * 32 + orr][j * 32 + oc + 1] = -v1;
            T[i * 32 + orr][j * 32 + oc + 2] = -v2;
            T[i * 32 + orr][j * 32 + oc + 3] = -v3;
            __syncthreads();
        }
    }
    // ---- writeback Linv (exact zeros above diagonal) ----
    {
        int r = tid >> 1, c0 = (tid & 1) * 64;
        float* dst = A + (long)(o + r) * 1024 + o + c0;
#pragma unroll
        for (int k = 0; k < 16; k++) {
            int c = c0 + 4 * k;
            float4 v = make_float4(T[r][c], T[r][c + 1], T[r][c + 2], T[r][c + 3]);
            *(float4*)(dst + 4 * k) = v;
        }
    }
    // ---- forward diag step: y = Linv @ z; last block also x = Linv^T y ----
    {
        int k = tid >> 1, c0 = (tid & 1) * 4;
        float4 v = *(const float4*)&Vp[(o + k) * 8 + c0];
        zs[k][c0] = v.x; zs[k][c0 + 1] = v.y; zs[k][c0 + 2] = v.z; zs[k][c0 + 3] = v.w;
    }
    __syncthreads();
    {
        int r = tid & 127, c0 = (tid >> 7) * 4;
        float y0 = 0, y1 = 0, y2 = 0, y3 = 0;
#pragma unroll 8
        for (int k = 0; k < 128; k++) {
            float l = T[r][k];
            y0 += l * zs[k][c0    ];
            y1 += l * zs[k][c0 + 1];
            y2 += l * zs[k][c0 + 2];
            y3 += l * zs[k][c0 + 3];
        }
        if (!last) {
            *(float4*)&Vp[(o + r) * 8 + c0] = make_float4(y0, y1, y2, y3);
        } else {
            __syncthreads();
            zs[r][c0] = y0; zs[r][c0+1] = y1; zs[r][c0+2] = y2; zs[r][c0+3] = y3;
            __syncthreads();
            float x0 = 0, x1 = 0, x2 = 0, x3 = 0;
#pragma unroll 8
            for (int k = 0; k < 128; k++) {
                float l = T[k][r];
                x0 += l * zs[k][c0    ];
                x1 += l * zs[k][c0 + 1];
                x2 += l * zs[k][c0 + 2];
                x3 += l * zs[k][c0 + 3];
            }
            *(float4*)&Vp[(o + r) * 8 + c0] = make_float4(x0, x1, x2, x3);
        }
    }
}

// ---------------- syrk body: A(bi,bj) -= L21_i @ L21_j^T (R11 form) ------------
__device__ void syrk_body(float* __restrict__ C, int o, int pti, int ptj, int b) {
    float* A = C + (long)b * 1048576;
    int bi = o + 128 + pti * 128, bj = o + 128 + ptj * 128;
    __shared__ float As[32][132];
    __shared__ float Bs[32][132];
    int tid = threadIdx.x;
    int tx = tid & 15, ty = tid >> 4;
    float acc[8][8] = {};
    int lr = tid >> 1;
    int lk = (tid & 1) * 16;
    bool diag = (bi == bj);
    for (int kc = 0; kc < 128; kc += 32) {
        {
            const float* src = A + (long)(bi + lr) * 1024 + o + kc + lk;
#pragma unroll
            for (int k4 = 0; k4 < 4; k4++) {
                float4 v = *(const float4*)(src + 4 * k4);
                As[lk + 4*k4    ][lr] = v.x;
                As[lk + 4*k4 + 1][lr] = v.y;
                As[lk + 4*k4 + 2][lr] = v.z;
                As[lk + 4*k4 + 3][lr] = v.w;
            }
            if (!diag) {
                const float* sb = A + (long)(bj + lr) * 1024 + o + kc + lk;
#pragma unroll
                for (int k4 = 0; k4 < 4; k4++) {
                    float4 v = *(const float4*)(sb + 4 * k4);
                    Bs[lk + 4*k4    ][lr] = v.x;
                    Bs[lk + 4*k4 + 1][lr] = v.y;
                    Bs[lk + 4*k4 + 2][lr] = v.z;
                    Bs[lk + 4*k4 + 3][lr] = v.w;
                }
            }
        }
        __syncthreads();
        {
            const float (*Bp)[132] = diag ? As : Bs;
#pragma unroll
            for (int k = 0; k < 32; k++) {
                float4 a0 = *(const float4*)&As[k][ty * 8];
                float4 a1 = *(const float4*)&As[k][ty * 8 + 4];
                float4 b0 = *(const float4*)&Bp[k][tx * 8];
                float4 b1 = *(const float4*)&Bp[k][tx * 8 + 4];
                float aa[8] = {a0.x,a0.y,a0.z,a0.w,a1.x,a1.y,a1.z,a1.w};
                float bb[8] = {b0.x,b0.y,b0.z,b0.w,b1.x,b1.y,b1.z,b1.w};
#pragma unroll
                for (int i = 0; i < 8; i++)
#pragma unroll
                    for (int j = 0; j < 8; j++) acc[i][j] += aa[i] * bb[j];
            }
        }
        __syncthreads();
    }
#pragma unroll
    for (int i = 0; i < 8; i++) {
        int r = bi + ty * 8 + i;
        float* dst = A + (long)r * 1024 + bj + tx * 8;
        if (!diag) {
            float4 p0 = *(const float4*)dst;
            float4 p1 = *(const float4*)(dst + 4);
            p0.x -= acc[i][0]; p0.y -= acc[i][1]; p0.z -= acc[i][2]; p0.w -= acc[i][3];
            p1.x -= acc[i][4]; p1.y -= acc[i][5]; p1.z -= acc[i][6]; p1.w -= acc[i][7];
            *(float4*)dst = p0;
            *(float4*)(dst + 4) = p1;
        } else {
#pragma unroll
            for (int j = 0; j < 8; j++) {
                int c = bj + tx * 8 + j;
                if (c <= r) dst[j] -= acc[i][j];
            }
        }
    }
}

// ---------------- fused launch: potf(s) [blocks 0-15] + ALL syrk(s-1) pairs
// except (0,0) (handled by potf's prologue) ------------------------------------
__global__ __launch_bounds__(256) void k_potf_syrk(float* __restrict__ C,
                                                   float* __restrict__ V,
                                                   int o, int last) {
    int bx = blockIdx.x;
    if (bx < 16) {
        potf_body(C, V, o, last, bx);
    } else {
        int v = bx - 16;
        int bb = v & 15;
        int p = (v >> 4) + 1;             // skip pair (0,0)
        int tii = row_of(p);
        int tjj = p - tii * (tii + 1) / 2;
        syrk_body(C, o - 128, tii, tjj, bb);
    }
}

// ---------------- TRSM-GEMM + fwd z-update -------------------------------------
__global__ __launch_bounds__(256) void k_trsmg(float* __restrict__ C,
                                               float* __restrict__ V, int o) {
    int b = blockIdx.y;
    float* A = C + (long)b * 1048576;
    float* Vp = V + (long)b * 8192;
    int bi = o + 128 + blockIdx.x * 128;
    const float* Linv = A + (long)o * 1024 + o;
    __shared__ float As[32][132];
    __shared__ float Ls[32][132];   // reused as ys (flat) in the tail
    int tid = threadIdx.x;
    int tx = tid & 15, ty = tid >> 4;
    float acc[8][8] = {};
    int lr = tid >> 1;
    int lk = (tid & 1) * 16;
    for (int kc = 0; kc < 128; kc += 32) {
        const float* src = A + (long)(bi + lr) * 1024 + o + kc + lk;
        const float* sl  = Linv + (long)lr * 1024 + kc + lk;
#pragma unroll
        for (int k4 = 0; k4 < 4; k4++) {
            float4 v = *(const float4*)(src + 4 * k4);
            As[lk + 4*k4    ][lr] = v.x;
            As[lk + 4*k4 + 1][lr] = v.y;
            As[lk + 4*k4 + 2][lr] = v.z;
            As[lk + 4*k4 + 3][lr] = v.w;
            float4 w = *(const float4*)(sl + 4 * k4);
            Ls[lk + 4*k4    ][lr] = w.x;
            Ls[lk + 4*k4 + 1][lr] = w.y;
            Ls[lk + 4*k4 + 2][lr] = w.z;
            Ls[lk + 4*k4 + 3][lr] = w.w;
        }
        __syncthreads();
#pragma unroll
        for (int k = 0; k < 32; k++) {
            float4 a0 = *(const float4*)&As[k][ty * 8];
            float4 a1 = *(const float4*)&As[k][ty * 8 + 4];
            float4 b0 = *(const float4*)&Ls[k][tx * 8];
            float4 b1 = *(const float4*)&Ls[k][tx * 8 + 4];
            float aa[8] = {a0.x,a0.y,a0.z,a0.w,a1.x,a1.y,a1.z,a1.w};
            float bb[8] = {b0.x,b0.y,b0.z,b0.w,b1.x,b1.y,b1.z,b1.w};
#pragma unroll
            for (int i = 0; i < 8; i++)
#pragma unroll
                for (int j = 0; j < 8; j++) acc[i][j] += aa[i] * bb[j];
        }
        __syncthreads();
    }
#pragma unroll
    for (int i = 0; i < 8; i++) {
        float* dst = A + (long)(bi + ty * 8 + i) * 1024 + o + tx * 8;
        *(float4*)dst       = make_float4(acc[i][0], acc[i][1], acc[i][2], acc[i][3]);
        *(float4*)(dst + 4) = make_float4(acc[i][4], acc[i][5], acc[i][6], acc[i][7]);
    }
    // tail: z_j -= L21 @ y_s (acc registers ARE L21; stream via LDS chunks)
    float* ysf = &Ls[0][0];
    {
        int k = tid >> 1, c0 = (tid & 1) * 4;
        float4 v = *(const float4*)&Vp[(o + k) * 8 + c0];
        ysf[k * 9 + c0] = v.x; ysf[k * 9 + c0 + 1] = v.y;
        ysf[k * 9 + c0 + 2] = v.z; ysf[k * 9 + c0 + 3] = v.w;
    }
    __syncthreads();
    float zacc0 = 0, zacc1 = 0, zacc2 = 0, zacc3 = 0;
    int zr = tid & 127, zc0 = (tid >> 7) * 4;
#pragma unroll
    for (int ch = 0; ch < 4; ch++) {
        if ((tx >> 2) == ch) {
            int cb = (tx & 3) * 8;
#pragma unroll
            for (int j = 0; j < 8; j++)
#pragma unroll
                for (int i = 0; i < 8; i++)
                    As[cb + j][ty * 8 + i] = acc[i][j];
        }
        __syncthreads();
#pragma unroll 8
        for (int k = 0; k < 32; k++) {
            float l = As[k][zr];
            const float* yp = &ysf[(ch * 32 + k) * 9 + zc0];
            zacc0 += l * yp[0]; zacc1 += l * yp[1];
            zacc2 += l * yp[2]; zacc3 += l * yp[3];
        }
        __syncthreads();
    }
    float* vp = &Vp[(bi + zr) * 8 + zc0];
    float4 old = *(const float4*)vp;
    old.x -= zacc0; old.y -= zacc1; old.z -= zacc2; old.w -= zacc3;
    *(float4*)vp = old;
}

// ---------------- backward step k: y_j -= L_{k,j}^T x_k (j<k, parallel) --------
__global__ __launch_bounds__(256) void k_bstep(const float* __restrict__ C,
                                               float* __restrict__ V, int k) {
    int b = blockIdx.y, j = blockIdx.x, tid = threadIdx.x;
    const float* A = C + (long)b * 1048576;
    float* Vp = V + (long)b * 8192;
    __shared__ float Lb[128][129];
    __shared__ float xs[128][9];
    __shared__ float ys[128][9];
    {
        int kk = tid >> 1, c0 = (tid & 1) * 4;
        float4 v = *(const float4*)&Vp[(k * 128 + kk) * 8 + c0];
        xs[kk][c0] = v.x; xs[kk][c0+1] = v.y; xs[kk][c0+2] = v.z; xs[kk][c0+3] = v.w;
    }
#pragma unroll
    for (int m = 0; m < 16; m++) {
        int e = tid + m * 256;
        int i = e >> 5, j4 = (e & 31) * 4;
        float4 v = *(const float4*)&A[(long)(k * 128 + i) * 1024 + j * 128 + j4];
        Lb[i][j4] = v.x; Lb[i][j4+1] = v.y; Lb[i][j4+2] = v.z; Lb[i][j4+3] = v.w;
    }
    __syncthreads();
    int r = tid & 127, c0 = (tid >> 7) * 4;
    float u0 = 0, u1 = 0, u2 = 0, u3 = 0;
#pragma unroll 8
    for (int kk = 0; kk < 128; kk++) {
        float l = Lb[kk][r];
        u0 += l * xs[kk][c0    ];
        u1 += l * xs[kk][c0 + 1];
        u2 += l * xs[kk][c0 + 2];
        u3 += l * xs[kk][c0 + 3];
    }
    float* vp = &Vp[(j * 128 + r) * 8 + c0];
    float4 old = *(const float4*)vp;
    old.x -= u0; old.y -= u1; old.z -= u2; old.w -= u3;
    if (j < k - 1) {
        *(float4*)vp = old;
    } else {
        ys[r][c0] = old.x; ys[r][c0+1] = old.y; ys[r][c0+2] = old.z; ys[r][c0+3] = old.w;
        __syncthreads();
        int o = j * 128;
#pragma unroll
        for (int m = 0; m < 16; m++) {
            int e = tid + m * 256;
            int i = e >> 5, j4 = (e & 31) * 4;
            float4 v = *(const float4*)&A[(long)(o + i) * 1024 + o + j4];
            Lb[i][j4] = v.x; Lb[i][j4+1] = v.y; Lb[i][j4+2] = v.z; Lb[i][j4+3] = v.w;
        }
        __syncthreads();
        float x0 = 0, x1 = 0, x2 = 0, x3 = 0;
#pragma unroll 8
        for (int kk = 0; kk < 128; kk++) {
            float l = Lb[kk][r];
            x0 += l * ys[kk][c0    ];
            x1 += l * ys[kk][c0 + 1];
            x2 += l * ys[kk][c0 + 2];
            x3 += l * ys[kk][c0 + 3];
        }
        *(float4*)vp = make_float4(x0, x1, x2, x3);
    }
}

// ---------------- fused output: out[q,:] = sum_k exp(-d(Qs_q,Ks_k)) X[k,:] -----
__global__ void k_out(const float* __restrict__ Qs, const float* __restrict__ Ks,
                      const float* __restrict__ X, float* __restrict__ out) {
    int b = blockIdx.x >> 4;
    int qc = blockIdx.x & 15;
    int t = threadIdx.x;
    int q = t & 63, ks = t >> 6;
    __shared__ float kx[1024][3];
    __shared__ __align__(16) float xv[1024][8];
    __shared__ float red[4][64][8];
    for (int i = t; i < 3072; i += 256) kx[i / 3][i % 3] = Ks[b * 3072 + i];
    for (int i = t; i < 8192; i += 256) xv[i >> 3][i & 7] = X[b * 8192 + i];
    __syncthreads();
    int gq = b * 1024 + qc * 64 + q;
    const float* qp = Qs + (long)gq * 3;
    float qx = qp[0], qy = qp[1], qz = qp[2];
    float acc[8] = {};
    int k0 = ks * 256;
#pragma unroll 2
    for (int k = k0; k < k0 + 256; k++) {
        float dx = qx - kx[k][0], dy = qy - kx[k][1], dz = qz - kx[k][2];
        float w = __expf(-sqrtf(dx * dx + dy * dy + dz * dz + 1e-12f));
        float4 xa = *(const float4*)&xv[k][0];
        float4 xb = *(const float4*)&xv[k][4];
        acc[0] += w * xa.x; acc[1] += w * xa.y; acc[2] += w * xa.z; acc[3] += w * xa.w;
        acc[4] += w * xb.x; acc[5] += w * xb.y; acc[6] += w * xb.z; acc[7] += w * xb.w;
    }
#pragma unroll
    for (int c = 0; c < 8; c++) red[ks][q][c] = acc[c];
    __syncthreads();
    if (ks == 0) {
        float* op = out + (long)gq * 8;
#pragma unroll
        for (int c = 0; c < 8; c++)
            op[c] = red[0][q][c] + red[1][q][c] + red[2][q][c] + red[3][q][c];
    }
}

extern "C" void kernel_launch(void* const* d_in, const int* in_sizes, int n_in,
                              void* d_out, int out_size, void* d_ws, size_t ws_size,
                              hipStream_t stream) {
    const float* KEY   = (const float*)d_in[0];
    const float* VALUE = (const float*)d_in[1];
    const float* QUERY = (const float*)d_in[2];
    const float* W1w = (const float*)d_in[3];  const float* W1b = (const float*)d_in[4];
    const float* W2w = (const float*)d_in[5];  const float* W2b = (const float*)d_in[6];
    const float* W3w = (const float*)d_in[7];  const float* W3b = (const float*)d_in[8];
    const float* Wv1w = (const float*)d_in[9]; const float* Wv1b = (const float*)d_in[10];
    const float* Wv2w = (const float*)d_in[11];const float* Wv2b = (const float*)d_in[12];
    const float* Wv3w = (const float*)d_in[13];const float* Wv3b = (const float*)d_in[14];

    float* ws  = (float*)d_ws;
    float* C    = ws;                 // 16*1024*1024
    float* Ks   = C + 16777216;       // 16*1024*3
    float* Qs   = Ks + 49152;
    float* Vs   = Qs + 49152;         // 16*1024*8 (z -> y -> x in place)
    float* W2T  = Vs + 131072;
    float* Wv2T = W2T + 16384;

    float* out = (float*)d_out;

    hipLaunchKernelGGL(k_transpose, dim3(128), dim3(256), 0, stream, W2w, Wv2w, W2T, Wv2T);
    hipLaunchKernelGGL(k_mlp_kq, dim3(1024), dim3(128), 0, stream,
                       KEY, Ks, QUERY, Qs, W1w, W1b, W2T, W2b, W3w, W3b);
    hipLaunchKernelGGL(k_mlp_v, dim3(1024), dim3(128), 0, stream,
                       VALUE, Vs, Wv1w, Wv1b, Wv2T, Wv2b, Wv3w, Wv3b);
    hipLaunchKernelGGL(k_buildC, dim3(65536), dim3(256), 0, stream, Ks, C);

    // factorization + fused forward substitution: 2 launches per step
    for (int s = 0; s < 8; s++) {
        int o = s * 128;
        int np = 0;
        if (s >= 1) { int ntp = 8 - s; np = ntp * (ntp + 1) / 2 - 1; }
        hipLaunchKernelGGL(k_potf_syrk, dim3(16 + np * 16), dim3(256), 0, stream,
                           C, Vs, o, (s == 7) ? 1 : 0);
        int nt = 7 - s;
        if (nt > 0)
            hipLaunchKernelGGL(k_trsmg, dim3(nt, 16), dim3(256), 0, stream, C, Vs, o);
    }
    // backward substitution: parallel right-looking (x_7 done inside last potf)
    for (int k = 7; k >= 1; k--)
        hipLaunchKernelGGL(k_bstep, dim3(k, 16), dim3(256), 0, stream, C, Vs, k);

    hipLaunchKernelGGL(k_out, dim3(256), dim3(256), 0, stream, Qs, Ks, Vs, out);
}